// Round 8
// baseline (189.426 us; speedup 1.0000x reference)
//
#include <hip/hip_runtime.h>
#include <math.h>

#define Bn 4
#define Sn 2048
#define Dn 1024
#define En 8
#define HDn 128
#define NG 32
#define MAXT 160
#define MAXN 1024   // max tokens per (b,e) group (n ~ 256 +- 15)

typedef __attribute__((ext_vector_type(8))) short bf16x8;
typedef __attribute__((ext_vector_type(4))) float f32x4;
typedef unsigned short u16;

__device__ __forceinline__ unsigned bf16_rn(float x) {
  unsigned u = __float_as_uint(x);
  return (u + 0x7fffu + ((u >> 16) & 1u)) >> 16;
}
__device__ __forceinline__ void bsplit(float x, unsigned& hi, unsigned& lo) {
  hi = bf16_rn(x);
  lo = bf16_rn(x - __uint_as_float(hi << 16));
}
__device__ __forceinline__ void gl16(const void* g, void* l) {
  __builtin_amdgcn_global_load_lds(
      (const __attribute__((address_space(1))) void*)g,
      (__attribute__((address_space(3))) void*)l, 16, 0, 0);
}
#define MFMA16(a, b, c) __builtin_amdgcn_mfma_f32_16x16x32_bf16((a), (b), (c), 0, 0, 0)

// ------- transpose+split helper: W[e][K][N] tile -> [e][N][K] bf16 hi/lo -------
__device__ __forceinline__ void prep_body(
    const float* __restrict__ W, u16* __restrict__ hiT, u16* __restrict__ loT,
    int Kdim, int Ndim, int e, int k0, int c0, float (*tile)[65])
{
  int t = threadIdx.x;
  int r = t >> 4, cc = (t & 15) << 2;
  const float* src = W + ((size_t)e * Kdim + k0) * Ndim + c0;
#pragma unroll
  for (int i = 0; i < 4; ++i) {
    float4 v = *(const float4*)(src + (size_t)(r + i * 16) * Ndim + cc);
    tile[r + i * 16][cc + 0] = v.x; tile[r + i * 16][cc + 1] = v.y;
    tile[r + i * 16][cc + 2] = v.z; tile[r + i * 16][cc + 3] = v.w;
  }
  __syncthreads();
#pragma unroll
  for (int i = 0; i < 4; ++i) {
    int oc = (t >> 4) + i * 16;
    int ok = (t & 15) << 2;
    float v0 = tile[ok + 0][oc], v1 = tile[ok + 1][oc];
    float v2 = tile[ok + 2][oc], v3 = tile[ok + 3][oc];
    unsigned h0,l0,h1,l1,h2,l2,h3,l3;
    bsplit(v0,h0,l0); bsplit(v1,h1,l1); bsplit(v2,h2,l2); bsplit(v3,h3,l3);
    size_t o = ((size_t)e * Ndim + c0 + oc) * Kdim + k0 + ok;
    *(ushort4*)(hiT + o) = make_ushort4((u16)h0,(u16)h1,(u16)h2,(u16)h3);
    *(ushort4*)(loT + o) = make_ushort4((u16)l0,(u16)l1,(u16)l2,(u16)l3);
  }
}

// ---- K1: merged prologue: RoPE+gate (blocks 0..2047), prep Wqkv (2048..2815),
// ----     prep Wff (2816..3071). launch_bounds(256,4): 128-VGPR budget so the
// ----     compiler can keep loads in flight (round-7: 32 VGPRs => serialized).
__global__ __launch_bounds__(256, 4) void k_prologue(
    const float* __restrict__ x, const float* __restrict__ Wg,
    const float* __restrict__ cosT, const float* __restrict__ sinT,
    const float* __restrict__ Wqkv, const float* __restrict__ Wff,
    u16* __restrict__ xh_hi, u16* __restrict__ xh_lo,
    u16* __restrict__ WqT_hi, u16* __restrict__ WqT_lo,
    u16* __restrict__ WfT_hi, u16* __restrict__ WfT_lo,
    int* __restrict__ expertArr, float* __restrict__ gateArr,
    int* __restrict__ done)
{
  __shared__ float tile[64][65];
  int bid = blockIdx.x;
  if (bid == 0 && threadIdx.x == 0) done[0] = 0;
  if (bid < 2048) {
    // ---- RoPE + gating, 1 wave per token, 4 tokens/block ----
    int wid = threadIdx.x >> 6, l = threadIdx.x & 63;
    int bs = (bid << 2) + wid;
    int s  = bs & (Sn - 1);
    const float* xrow = x + (size_t)bs * Dn;
    int j0 = l << 4;
    int hb = j0 & ~127;
    int jj = j0 & 127;
    float v[16];
    if (jj < 64) {
      const float* pe = xrow + hb + 64 + jj;
      float a[16];
      *(float4*)(a + 0)  = *(const float4*)(pe + 0);
      *(float4*)(a + 4)  = *(const float4*)(pe + 4);
      *(float4*)(a + 8)  = *(const float4*)(pe + 8);
      *(float4*)(a + 12) = *(const float4*)(pe + 12);
      int p0 = jj >> 1;
      float cbuf[8], sbuf[8];
      *(float4*)(cbuf + 0) = *(const float4*)(cosT + s * 32 + p0);
      *(float4*)(cbuf + 4) = *(const float4*)(cosT + s * 32 + p0 + 4);
      *(float4*)(sbuf + 0) = *(const float4*)(sinT + s * 32 + p0);
      *(float4*)(sbuf + 4) = *(const float4*)(sinT + s * 32 + p0 + 4);
#pragma unroll
      for (int i = 0; i < 8; ++i) {
        float c  = cbuf[i];
        float sn = sbuf[i];
        v[2 * i]     = a[2 * i] * c - a[2 * i + 1] * sn;
        v[2 * i + 1] = a[2 * i] * sn + a[2 * i + 1] * c;
      }
    } else {
      const float* np = xrow + hb + (jj - 64);
      *(float4*)(v + 0)  = *(const float4*)(np + 0);
      *(float4*)(v + 4)  = *(const float4*)(np + 4);
      *(float4*)(v + 8)  = *(const float4*)(np + 8);
      *(float4*)(v + 12) = *(const float4*)(np + 12);
    }
    u16 hh[16] __attribute__((aligned(16)));
    u16 ll[16] __attribute__((aligned(16)));
#pragma unroll
    for (int i = 0; i < 16; ++i) {
      unsigned h, lo;
      bsplit(v[i], h, lo);
      hh[i] = (u16)h; ll[i] = (u16)lo;
    }
    *(uint4*)(xh_hi + (size_t)bs * Dn + j0)     = *(uint4*)(hh);
    *(uint4*)(xh_hi + (size_t)bs * Dn + j0 + 8) = *(uint4*)(hh + 8);
    *(uint4*)(xh_lo + (size_t)bs * Dn + j0)     = *(uint4*)(ll);
    *(uint4*)(xh_lo + (size_t)bs * Dn + j0 + 8) = *(uint4*)(ll + 8);

    // gating: chunked preload (8 float4 in flight); FMA order identical to r7
    float pl[8] = {0.f, 0.f, 0.f, 0.f, 0.f, 0.f, 0.f, 0.f};
    const float* wr = Wg + (size_t)j0 * En;
#pragma unroll
    for (int c4 = 0; c4 < 4; ++c4) {
      float4 wbuf[8];
#pragma unroll
      for (int k = 0; k < 8; ++k) wbuf[k] = *(const float4*)(wr + c4 * 32 + k * 4);
#pragma unroll
      for (int i2 = 0; i2 < 4; ++i2) {
        float xv = v[c4 * 4 + i2];
        float4 w0 = wbuf[i2 * 2], w1 = wbuf[i2 * 2 + 1];
        pl[0] += xv * w0.x; pl[1] += xv * w0.y; pl[2] += xv * w0.z; pl[3] += xv * w0.w;
        pl[4] += xv * w1.x; pl[5] += xv * w1.y; pl[6] += xv * w1.z; pl[7] += xv * w1.w;
      }
    }
#pragma unroll
    for (int off = 1; off < 64; off <<= 1) {
#pragma unroll
      for (int e = 0; e < 8; ++e) pl[e] += __shfl_xor(pl[e], off, 64);
    }
    float m = pl[0]; int be = 0;
#pragma unroll
    for (int e = 1; e < 8; ++e) if (pl[e] > m) { m = pl[e]; be = e; }   // first max wins
    float ss = 0.f;
#pragma unroll
    for (int e = 0; e < 8; ++e) ss += expf(pl[e] - m);
    if (l == 0) {
      expertArr[bs] = be;
      gateArr[bs] = 1.0f / ss;
    }
  } else if (bid < 2048 + 768) {
    int id = bid - 2048;               // 8 experts * (16 k-tiles * 6 c-tiles)
    int e = id / 96, r2 = id % 96;
    prep_body(Wqkv, WqT_hi, WqT_lo, Dn, 384, e, (r2 / 6) << 6, (r2 % 6) << 6, tile);
  } else {
    int id = bid - 2816;               // 8 experts * (2 k-tiles * 16 c-tiles)
    int e = id >> 5, r2 = id & 31;
    prep_body(Wff, WfT_hi, WfT_lo, HDn, Dn, e, (r2 >> 4) << 6, (r2 & 15) << 6, tile);
  }
}

// ---------------- K2: stable per-(b,e) token lists + tile table (last block) ----------------
__global__ __launch_bounds__(256) void k_route(
    const int* __restrict__ expertArr, int* __restrict__ idx, int* __restrict__ cnt,
    int* __restrict__ tileg, int* __restrict__ tilem, int* __restrict__ ntile,
    int* __restrict__ done)
{
  int g = blockIdx.x;
  int b = g >> 3, e = g & 7;
  int t = threadIdx.x;
  __shared__ int wtot[4];
  __shared__ int base;
  if (t == 0) base = 0;
  __syncthreads();
  for (int c = 0; c < Sn; c += 256) {
    int s = c + t;
    int pred = (expertArr[b * Sn + s] == e) ? 1 : 0;
    unsigned long long mask = __ballot(pred);
    int ln = t & 63, wv = t >> 6;
    int wpre = __popcll(mask & ((1ull << ln) - 1ull));
    if (ln == 63) wtot[wv] = wpre + pred;
    __syncthreads();
    int woff = 0;
    for (int w = 0; w < wv; ++w) woff += wtot[w];
    int tot = wtot[0] + wtot[1] + wtot[2] + wtot[3];
    if (pred) idx[(g << 11) + base + woff + wpre] = s;
    __syncthreads();
    if (t == 0) base += tot;
    __syncthreads();
  }
  if (t == 0) {
    cnt[g] = base;
    __threadfence();
    if (atomicAdd(done, 1) == NG - 1) {
      int tc = 0;
      for (int gg = 0; gg < NG; ++gg) {
        int nn = __hip_atomic_load(&cnt[gg], __ATOMIC_ACQUIRE, __HIP_MEMORY_SCOPE_AGENT);
        for (int m0 = 0; m0 < nn && tc < MAXT; m0 += 64) { tileg[tc] = gg; tilem[tc] = m0; ++tc; }
      }
      ntile[0] = tc;
    }
  }
}

// ------- K3: grouped QKV GEMM, MFMA bf16x3, BM=64 x BN=192 x BK=32 -------
// Counted-vmcnt pipeline (T4): 8 global_load_lds per wave per iter; never drain
// to 0 in the main loop. Raw s_barrier + lgkmcnt-only drain for read-protect.
__global__ __launch_bounds__(256) void k_qkv(
    const u16* __restrict__ xh_hi, const u16* __restrict__ xh_lo,
    const u16* __restrict__ WqT_hi, const u16* __restrict__ WqT_lo,
    const int* __restrict__ idx, const int* __restrict__ cnt,
    u16* __restrict__ qkv_hi, u16* __restrict__ qkv_lo,
    u16* __restrict__ vT_hi, u16* __restrict__ vT_lo)
{
  extern __shared__ unsigned char LDS[];
  int bid = blockIdx.x;            // 384 = 8 xcd * 4 groups * 12 slots
  int r8 = bid & 7, q = bid >> 3;  // q 0..47
  int g = r8 + ((q & 3) << 3);     // all 32 groups
  int slot = q >> 2;               // 0..11
  int m0 = (slot >> 1) << 6;       // 6 m-tiles (covers n<=384)
  int n0 = (slot & 1) * 192;       // 2 n0 passes
  int n = cnt[g];
  if (m0 >= n) return;
  int b = g >> 3, e = g & 7;
  const int* idxg = idx + (g << 11);
  int t = threadIdx.x;
  int w = t >> 6, l = t & 63;
  int lc = l & 15, lq = l >> 4;

  int srow = t >> 2;
  int sslot = (t & 3) ^ ((srow >> 1) & 3);
  int rgs = m0 + srow; rgs = rgs < n ? rgs : n - 1;
  size_t aoffR = ((size_t)(b * Sn + idxg[rgs])) * Dn + sslot * 8;
  size_t boffR0 = ((size_t)e * 384 + n0 + srow) * Dn + sslot * 8;
  unsigned dst = (unsigned)t << 4;

  f32x4 acc[4][3];
#pragma unroll
  for (int i = 0; i < 4; ++i)
#pragma unroll
    for (int j = 0; j < 3; ++j) acc[i][j] = (f32x4){0.f, 0.f, 0.f, 0.f};

  unsigned off = (unsigned)((lq ^ ((lc >> 1) & 3)) << 4);

#define STAGE(bb, k0)                                                 \
  do {                                                                \
    gl16(xh_hi + aoffR + (k0), LDS + (bb) + dst);                     \
    gl16(xh_lo + aoffR + (k0), LDS + (bb) + 4096 + dst);              \
    gl16(WqT_hi + boffR0 + (k0), LDS + (bb) + 8192 + dst);            \
    gl16(WqT_hi + boffR0 + (size_t)64 * Dn + (k0), LDS + (bb) + 12288 + dst); \
    gl16(WqT_hi + boffR0 + (size_t)128 * Dn + (k0), LDS + (bb) + 16384 + dst);\
    gl16(WqT_lo + boffR0 + (k0), LDS + (bb) + 20480 + dst);           \
    gl16(WqT_lo + boffR0 + (size_t)64 * Dn + (k0), LDS + (bb) + 24576 + dst); \
    gl16(WqT_lo + boffR0 + (size_t)128 * Dn + (k0), LDS + (bb) + 28672 + dst);\
  } while (0)

  STAGE(0, 0);
  asm volatile("s_waitcnt vmcnt(0)" ::: "memory");
  __builtin_amdgcn_s_barrier();
  for (int tt = 0; tt < 32; ++tt) {
    unsigned cur = (tt & 1) ? 32768u : 0u;
    if (tt < 31) {
      STAGE(cur ^ 32768u, (tt + 1) * 32);
      asm volatile("s_waitcnt vmcnt(8)" ::: "memory");   // current tile's 8 done
    } else {
      asm volatile("s_waitcnt vmcnt(0)" ::: "memory");
    }
    __builtin_amdgcn_s_barrier();                        // cur buffer ready
    bf16x8 ah[4], al[4], bh[3], bl[3];
#pragma unroll
    for (int fi = 0; fi < 4; ++fi) {
      unsigned ab = cur + (unsigned)((fi * 16 + lc) * 64) + off;
      ah[fi] = *(const bf16x8*)(LDS + ab);
      al[fi] = *(const bf16x8*)(LDS + ab + 4096);
    }
#pragma unroll
    for (int fj = 0; fj < 3; ++fj) {
      unsigned bb2 = cur + 8192u + (unsigned)((w * 48 + fj * 16 + lc) * 64) + off;
      bh[fj] = *(const bf16x8*)(LDS + bb2);
      bl[fj] = *(const bf16x8*)(LDS + bb2 + 12288);
    }
    __builtin_amdgcn_s_setprio(1);
#pragma unroll
    for (int fi = 0; fi < 4; ++fi)
#pragma unroll
      for (int fj = 0; fj < 3; ++fj) {
        acc[fi][fj] = MFMA16(ah[fi], bh[fj], acc[fi][fj]);
        acc[fi][fj] = MFMA16(al[fi], bh[fj], acc[fi][fj]);
        acc[fi][fj] = MFMA16(ah[fi], bl[fj], acc[fi][fj]);
      }
    __builtin_amdgcn_s_setprio(0);
    asm volatile("s_waitcnt lgkmcnt(0)" ::: "memory");   // ds_reads drained
    __builtin_amdgcn_sched_barrier(0);
    __builtin_amdgcn_s_barrier();                        // safe to overwrite cur
  }
#undef STAGE

#pragma unroll
  for (int fi = 0; fi < 4; ++fi) {
#pragma unroll
    for (int rr = 0; rr < 4; ++rr) {
      int rg = m0 + fi * 16 + lq * 4 + rr;
      if (rg < n) {
        int tok = idxg[rg];
#pragma unroll
        for (int fj = 0; fj < 3; ++fj) {
          int col = n0 + w * 48 + fj * 16 + lc;
          unsigned h, lo2;
          bsplit(acc[fi][fj][rr], h, lo2);
          if (col < 256) {
            size_t o = (size_t)(b * Sn + tok) * 384 + col;
            qkv_hi[o] = (u16)h; qkv_lo[o] = (u16)lo2;
          } else {
            size_t o = ((size_t)g * HDn + (col - 256)) * MAXN + rg;
            vT_hi[o] = (u16)h; vT_lo[o] = (u16)lo2;
          }
        }
      }
    }
  }
}

// ------- K4: grouped flash attention via MFMA bf16x3 (+T5 setprio) -------
__global__ __launch_bounds__(256) void k_attn(
    const u16* __restrict__ qkv_hi, const u16* __restrict__ qkv_lo,
    const u16* __restrict__ vT_hi, const u16* __restrict__ vT_lo,
    const int* __restrict__ idx, const int* __restrict__ cnt,
    const int* __restrict__ tileg, const int* __restrict__ tilem,
    const int* __restrict__ ntile,
    u16* __restrict__ ctx_hi, u16* __restrict__ ctx_lo)
{
  extern __shared__ unsigned char LDS[];
  int tid = blockIdx.x;
  if (tid >= ntile[0]) return;
  int g = tileg[tid], m0 = tilem[tid];
  int n = cnt[g];
  int b = g >> 3;
  const int* idxg = idx + (g << 11);
  int t = threadIdx.x, wid = t >> 6, l = t & 63;
  int lc = l & 15, lq = l >> 4;
  const float scale = 0.08838834764831845f;   // 1/sqrt(128)

  int qrg = m0 + wid * 16 + lc; qrg = qrg < n ? qrg : n - 1;
  size_t qoff = (size_t)(b * Sn + idxg[qrg]) * 384 + lq * 8;
  bf16x8 Qhi[4], Qlo[4];
#pragma unroll
  for (int ks = 0; ks < 4; ++ks) {
    Qhi[ks] = *(const bf16x8*)(qkv_hi + qoff + ks * 32);
    Qlo[ks] = *(const bf16x8*)(qkv_lo + qoff + ks * 32);
  }

  f32x4 acc[8];
#pragma unroll
  for (int i = 0; i < 8; ++i) acc[i] = (f32x4){0.f, 0.f, 0.f, 0.f};
  float m_r[4] = {-1e30f, -1e30f, -1e30f, -1e30f};
  float l_r[4] = {0.f, 0.f, 0.f, 0.f};

  size_t vbase = ((size_t)g * HDn + lc) * MAXN + lq * 8;
  unsigned pbase = 65536u + wid * 4096u;

#define STAGEK(bufb, kc)                                                     \
  do {                                                                       \
    unsigned bb = (bufb);                                                    \
    for (int j = 0; j < 4; ++j) {                                            \
      int c = wid * 4 + j;                                                   \
      int row = (kc) + c * 4 + lq;                                           \
      int rg = row < n ? row : n - 1;                                        \
      int srcslot = lc ^ (((c & 1) << 2) | lq);                              \
      size_t soff = (size_t)(b * Sn + idxg[rg]) * 384 + 128 + srcslot * 8;   \
      gl16(qkv_hi + soff, LDS + bb + c * 1024);                              \
      gl16(qkv_lo + soff, LDS + bb + 16384 + c * 1024);                      \
    }                                                                        \
  } while (0)

  int nt = (n + 63) >> 6;
  STAGEK(0, 0);
  __syncthreads();

  for (int tt = 0; tt < nt; ++tt) {
    unsigned cur = (tt & 1) ? 32768u : 0u;
    if (tt + 1 < nt) STAGEK(cur ^ 32768u, (tt + 1) * 64);
    int kc = tt * 64;

    f32x4 Sf[4];
#pragma unroll
    for (int kf = 0; kf < 4; ++kf) Sf[kf] = (f32x4){0.f, 0.f, 0.f, 0.f};
    __builtin_amdgcn_s_setprio(1);
#pragma unroll
    for (int ks = 0; ks < 4; ++ks) {
#pragma unroll
      for (int kf = 0; kf < 4; ++kf) {
        int row = kf * 16 + lc;
        unsigned byte = cur + row * 256 + ((((ks << 2) | lq) ^ (row & 7)) << 4);
        bf16x8 kh = *(const bf16x8*)(LDS + byte);
        bf16x8 kl = *(const bf16x8*)(LDS + byte + 16384);
        Sf[kf] = MFMA16(Qhi[ks], kh, Sf[kf]);
        Sf[kf] = MFMA16(Qlo[ks], kh, Sf[kf]);
        Sf[kf] = MFMA16(Qhi[ks], kl, Sf[kf]);
      }
    }
    __builtin_amdgcn_s_setprio(0);

    float mloc[4] = {-1e30f, -1e30f, -1e30f, -1e30f};
#pragma unroll
    for (int kf = 0; kf < 4; ++kf) {
#pragma unroll
      for (int r = 0; r < 4; ++r) {
        int key = kc + kf * 16 + lc;
        float s = (key < n) ? Sf[kf][r] * scale : -1e30f;
        Sf[kf][r] = s;
        mloc[r] = fmaxf(mloc[r], s);
      }
    }
#pragma unroll
    for (int off = 1; off < 16; off <<= 1) {
#pragma unroll
      for (int r = 0; r < 4; ++r) mloc[r] = fmaxf(mloc[r], __shfl_xor(mloc[r], off, 64));
    }
    float corr[4], rs[4] = {0.f, 0.f, 0.f, 0.f};
#pragma unroll
    for (int r = 0; r < 4; ++r) {
      float mn = fmaxf(m_r[r], mloc[r]);
      corr[r] = expf(m_r[r] - mn);
      m_r[r] = mn;
    }
#pragma unroll
    for (int kf = 0; kf < 4; ++kf) {
#pragma unroll
      for (int r = 0; r < 4; ++r) {
        float p = expf(Sf[kf][r] - m_r[r]);
        rs[r] += p;
        unsigned ph, plo;
        bsplit(p, ph, plo);
        int prow = (lq << 2) | r;
        int slot = (kf << 1) | (lc >> 3);
        unsigned pb = pbase + prow * 128 + ((slot ^ (prow & 7)) << 4) + ((lc & 7) << 1);
        *(u16*)(LDS + pb) = (u16)ph;
        *(u16*)(LDS + pb + 2048) = (u16)plo;
      }
    }
#pragma unroll
    for (int off = 1; off < 16; off <<= 1) {
#pragma unroll
      for (int r = 0; r < 4; ++r) rs[r] += __shfl_xor(rs[r], off, 64);
    }
#pragma unroll
    for (int r = 0; r < 4; ++r) l_r[r] = l_r[r] * corr[r] + rs[r];
#pragma unroll
    for (int df = 0; df < 8; ++df)
#pragma unroll
      for (int r = 0; r < 4; ++r) acc[df][r] *= corr[r];

#pragma unroll
    for (int ks2 = 0; ks2 < 2; ++ks2) {
      unsigned pr = pbase + lc * 128 + ((((ks2 << 2) | lq) ^ (lc & 7)) << 4);
      bf16x8 pa = *(const bf16x8*)(LDS + pr);
      bf16x8 pl = *(const bf16x8*)(LDS + pr + 2048);
      __builtin_amdgcn_s_setprio(1);
#pragma unroll
      for (int df = 0; df < 8; ++df) {
        size_t vo = vbase + (size_t)(df * 16) * MAXN + kc + ks2 * 32;
        bf16x8 vh = *(const bf16x8*)(vT_hi + vo);
        bf16x8 vl = *(const bf16x8*)(vT_lo + vo);
        acc[df] = MFMA16(pa, vh, acc[df]);
        acc[df] = MFMA16(pl, vh, acc[df]);
        acc[df] = MFMA16(pa, vl, acc[df]);
      }
      __builtin_amdgcn_s_setprio(0);
    }
    __syncthreads();
  }
#undef STAGEK

#pragma unroll
  for (int r = 0; r < 4; ++r) {
    int rg = m0 + wid * 16 + (lq << 2) + r;
    if (rg < n) {
      int tok = idxg[rg];
      float inv = 1.0f / l_r[r];
      size_t o = (size_t)(b * Sn + tok) * HDn + lc;
#pragma unroll
      for (int df = 0; df < 8; ++df) {
        unsigned h, lo2;
        bsplit(acc[df][r] * inv, h, lo2);
        ctx_hi[o + df * 16] = (u16)h;
        ctx_lo[o + df * 16] = (u16)lo2;
      }
    }
  }
}

// ---------------- K5: out projection via MFMA bf16x3 + gate + scatter ----------------
__global__ __launch_bounds__(256) void k_out(
    const u16* __restrict__ ctx_hi, const u16* __restrict__ ctx_lo,
    const u16* __restrict__ WfT_hi, const u16* __restrict__ WfT_lo,
    const float* __restrict__ bff,
    const int* __restrict__ idx, const int* __restrict__ cnt,
    const int* __restrict__ tileg, const int* __restrict__ tilem,
    const int* __restrict__ ntile,
    const float* __restrict__ gateArr,
    float* __restrict__ out)
{
  int tid = blockIdx.x;
  if (tid >= ntile[0]) return;
  int g = tileg[tid], m0 = tilem[tid];
  int n = cnt[g];
  int b = g >> 3, e = g & 7;
  const int* idxg = idx + (g << 11);
  int t = threadIdx.x, wid = t >> 6, l = t & 63;
  int lc = l & 15, lq = l >> 4;
  int n0 = blockIdx.y * 256 + wid * 64;

  f32x4 acc[4][4];
#pragma unroll
  for (int i = 0; i < 4; ++i)
#pragma unroll
    for (int j = 0; j < 4; ++j) acc[i][j] = (f32x4){0.f, 0.f, 0.f, 0.f};

  size_t aoff[4];
#pragma unroll
  for (int fi = 0; fi < 4; ++fi) {
    int rg = m0 + fi * 16 + lc; rg = rg < n ? rg : n - 1;
    aoff[fi] = ((size_t)(b * Sn + idxg[rg])) * HDn + lq * 8;
  }
  size_t boff[4];
#pragma unroll
  for (int fj = 0; fj < 4; ++fj)
    boff[fj] = ((size_t)e * Dn + n0 + fj * 16 + lc) * HDn + lq * 8;

#pragma unroll
  for (int ks = 0; ks < 4; ++ks) {
    int ko = ks * 32;
    bf16x8 ah[4], al[4], bh[4], bl[4];
#pragma unroll
    for (int fi = 0; fi < 4; ++fi) {
      ah[fi] = *(const bf16x8*)(ctx_hi + aoff[fi] + ko);
      al[fi] = *(const bf16x8*)(ctx_lo + aoff[fi] + ko);
    }
#pragma unroll
    for (int fj = 0; fj < 4; ++fj) {
      bh[fj] = *(const bf16x8*)(WfT_hi + boff[fj] + ko);
      bl[fj] = *(const bf16x8*)(WfT_lo + boff[fj] + ko);
    }
#pragma unroll
    for (int fi = 0; fi < 4; ++fi)
#pragma unroll
      for (int fj = 0; fj < 4; ++fj) {
        acc[fi][fj] = MFMA16(ah[fi], bh[fj], acc[fi][fj]);
        acc[fi][fj] = MFMA16(al[fi], bh[fj], acc[fi][fj]);
        acc[fi][fj] = MFMA16(ah[fi], bl[fj], acc[fi][fj]);
      }
  }

  float bv[4];
#pragma unroll
  for (int fj = 0; fj < 4; ++fj) bv[fj] = bff[n0 + fj * 16 + lc];

#pragma unroll
  for (int fi = 0; fi < 4; ++fi) {
#pragma unroll
    for (int rr = 0; rr < 4; ++rr) {
      int rg = m0 + fi * 16 + lq * 4 + rr;
      if (rg < n) {
        int tok = idxg[rg];
        float gt = gateArr[b * Sn + tok];
        float* orow = out + ((size_t)(b * Sn + tok)) * Dn + n0 + lc;
#pragma unroll
        for (int fj = 0; fj < 4; ++fj)
          orow[fj * 16] = (acc[fi][fj][rr] + bv[fj]) * gt;
      }
    }
  }
}

extern "C" void kernel_launch(void* const* d_in, const int* in_sizes, int n_in,
                              void* d_out, int out_size, void* d_ws, size_t ws_size,
                              hipStream_t stream) {
  const float* x    = (const float*)d_in[0];
  const float* Wg   = (const float*)d_in[1];
  const float* Wqkv = (const float*)d_in[2];
  const float* Wff  = (const float*)d_in[3];
  const float* bff  = (const float*)d_in[4];
  const float* cosT = (const float*)d_in[5];
  const float* sinT = (const float*)d_in[6];
  float* out = (float*)d_out;

  size_t off = 0;
  auto carve = [&](size_t bytes) -> void* {
    void* p = (char*)d_ws + off;
    off += (bytes + 255) & ~(size_t)255;
    return p;
  };
  u16* xh_hi  = (u16*)carve((size_t)Bn * Sn * Dn * 2);
  u16* xh_lo  = (u16*)carve((size_t)Bn * Sn * Dn * 2);
  u16* WqT_hi = (u16*)carve((size_t)En * 384 * Dn * 2);
  u16* WqT_lo = (u16*)carve((size_t)En * 384 * Dn * 2);
  u16* WfT_hi = (u16*)carve((size_t)En * Dn * HDn * 2);
  u16* WfT_lo = (u16*)carve((size_t)En * Dn * HDn * 2);
  u16* qkv_hi = (u16*)carve((size_t)Bn * Sn * 384 * 2);
  u16* qkv_lo = (u16*)carve((size_t)Bn * Sn * 384 * 2);
  u16* vT_hi  = (u16*)carve((size_t)NG * HDn * MAXN * 2);
  u16* vT_lo  = (u16*)carve((size_t)NG * HDn * MAXN * 2);
  u16* ctx_hi = (u16*)carve((size_t)Bn * Sn * HDn * 2);
  u16* ctx_lo = (u16*)carve((size_t)Bn * Sn * HDn * 2);
  float* gateArr = (float*)carve((size_t)Bn * Sn * sizeof(float));
  int*   expertA = (int*)carve((size_t)Bn * Sn * sizeof(int));
  int*   idx     = (int*)carve((size_t)NG * Sn * sizeof(int));
  int*   cnt     = (int*)carve((size_t)NG * sizeof(int));
  int*   tileg   = (int*)carve((size_t)MAXT * sizeof(int));
  int*   tilem   = (int*)carve((size_t)MAXT * sizeof(int));
  int*   ntile   = (int*)carve(256);
  int*   done    = (int*)carve(256);
  (void)ws_size; (void)in_sizes; (void)n_in; (void)out_size;

  hipFuncSetAttribute((const void*)k_attn, hipFuncAttributeMaxDynamicSharedMemorySize, 81920);

  k_prologue<<<dim3(3072), dim3(256), 0, stream>>>(x, Wg, cosT, sinT, Wqkv, Wff,
      xh_hi, xh_lo, WqT_hi, WqT_lo, WfT_hi, WfT_lo, expertA, gateArr, done);
  k_route<<<dim3(NG), dim3(256), 0, stream>>>(expertA, idx, cnt, tileg, tilem, ntile, done);
  k_qkv<<<dim3(384), dim3(256), 65536, stream>>>(xh_hi, xh_lo, WqT_hi, WqT_lo, idx, cnt, qkv_hi, qkv_lo, vT_hi, vT_lo);
  k_attn<<<dim3(MAXT), dim3(256), 81920, stream>>>(qkv_hi, qkv_lo, vT_hi, vT_lo, idx, cnt, tileg, tilem, ntile, ctx_hi, ctx_lo);
  k_out<<<dim3(MAXT, 4), dim3(256), 0, stream>>>(ctx_hi, ctx_lo, WfT_hi, WfT_lo, bff, idx, cnt, tileg, tilem, ntile, gateArr, out);
}

// Round 9
// 169.703 us; speedup vs baseline: 1.1162x; 1.1162x over previous
//
#include <hip/hip_runtime.h>
#include <math.h>

#define Bn 4
#define Sn 2048
#define Dn 1024
#define En 8
#define HDn 128
#define NG 32
#define MAXT 160
#define MAXN 1024   // max tokens per (b,e) group (n ~ 256 +- 15)

typedef __attribute__((ext_vector_type(8))) short bf16x8;
typedef __attribute__((ext_vector_type(4))) float f32x4;
typedef unsigned short u16;

__device__ __forceinline__ unsigned bf16_rn(float x) {
  unsigned u = __float_as_uint(x);
  return (u + 0x7fffu + ((u >> 16) & 1u)) >> 16;
}
__device__ __forceinline__ void bsplit(float x, unsigned& hi, unsigned& lo) {
  hi = bf16_rn(x);
  lo = bf16_rn(x - __uint_as_float(hi << 16));
}
__device__ __forceinline__ void gl16(const void* g, void* l) {
  __builtin_amdgcn_global_load_lds(
      (const __attribute__((address_space(1))) void*)g,
      (__attribute__((address_space(3))) void*)l, 16, 0, 0);
}
#define MFMA16(a, b, c) __builtin_amdgcn_mfma_f32_16x16x32_bf16((a), (b), (c), 0, 0, 0)

// ------- transpose+split helper: W[e][K][N] tile -> [e][N][K] bf16 hi/lo -------
__device__ __forceinline__ void prep_body(
    const float* __restrict__ W, u16* __restrict__ hiT, u16* __restrict__ loT,
    int Kdim, int Ndim, int e, int k0, int c0, float (*tile)[65])
{
  int t = threadIdx.x;
  int r = t >> 4, cc = (t & 15) << 2;
  const float* src = W + ((size_t)e * Kdim + k0) * Ndim + c0;
#pragma unroll
  for (int i = 0; i < 4; ++i) {
    float4 v = *(const float4*)(src + (size_t)(r + i * 16) * Ndim + cc);
    tile[r + i * 16][cc + 0] = v.x; tile[r + i * 16][cc + 1] = v.y;
    tile[r + i * 16][cc + 2] = v.z; tile[r + i * 16][cc + 3] = v.w;
  }
  __syncthreads();
#pragma unroll
  for (int i = 0; i < 4; ++i) {
    int oc = (t >> 4) + i * 16;
    int ok = (t & 15) << 2;
    float v0 = tile[ok + 0][oc], v1 = tile[ok + 1][oc];
    float v2 = tile[ok + 2][oc], v3 = tile[ok + 3][oc];
    unsigned h0,l0,h1,l1,h2,l2,h3,l3;
    bsplit(v0,h0,l0); bsplit(v1,h1,l1); bsplit(v2,h2,l2); bsplit(v3,h3,l3);
    size_t o = ((size_t)e * Ndim + c0 + oc) * Kdim + k0 + ok;
    *(ushort4*)(hiT + o) = make_ushort4((u16)h0,(u16)h1,(u16)h2,(u16)h3);
    *(ushort4*)(loT + o) = make_ushort4((u16)l0,(u16)l1,(u16)l2,(u16)l3);
  }
}

// ---- K1: merged prologue: RoPE+gate (blocks 0..2047), prep Wqkv (2048..2815),
// ----     prep Wff (2816..3071). Strided lane ownership j = c*64 + l so every
// ----     global access is coalesced (r8 was L1-transaction-bound: j0=l*16
// ----     ownership put each lane's float4 in its own cache line).
__global__ __launch_bounds__(256) void k_prologue(
    const float* __restrict__ x, const float* __restrict__ Wg,
    const float* __restrict__ cosT, const float* __restrict__ sinT,
    const float* __restrict__ Wqkv, const float* __restrict__ Wff,
    u16* __restrict__ xh_hi, u16* __restrict__ xh_lo,
    u16* __restrict__ WqT_hi, u16* __restrict__ WqT_lo,
    u16* __restrict__ WfT_hi, u16* __restrict__ WfT_lo,
    int* __restrict__ expertArr, float* __restrict__ gateArr,
    int* __restrict__ done)
{
  __shared__ float tile[64][65];
  int bid = blockIdx.x;
  if (bid == 0 && threadIdx.x == 0) done[0] = 0;
  if (bid < 2048) {
    // ---- RoPE + gating, 1 wave per token; lane l owns elements {128d+l, 128d+64+l} ----
    int wid = threadIdx.x >> 6, l = threadIdx.x & 63;
    int bs = (bid << 2) + wid;
    int s  = bs & (Sn - 1);
    const float* xrow = x + (size_t)bs * Dn;
    float xa[8], xb[8];
#pragma unroll
    for (int d = 0; d < 8; ++d) {
      xa[d] = xrow[d * 128 + l];        // nope source for element 128d+64+l
      xb[d] = xrow[d * 128 + 64 + l];   // pe source for element 128d+l (jj=l)
    }
    float ce = cosT[s * 32 + (l >> 1)];
    float sn = sinT[s * 32 + (l >> 1)];
    float ve[8];                         // value of element 128d+l (rotated)
#pragma unroll
    for (int d = 0; d < 8; ++d) {
      float self = xb[d];
      float part = __shfl_xor(self, 1, 64);
      // jj=l even: re=self, im=part -> re*c - im*s ; jj odd: re=part, im=self -> re*s + im*c
      ve[d] = (l & 1) ? (part * sn + self * ce) : (self * ce - part * sn);
    }
    // stores: element 128d+l = ve[d]; element 128d+64+l = xa[d]  (coalesced u16)
    size_t obase = (size_t)bs * Dn + l;
#pragma unroll
    for (int d = 0; d < 8; ++d) {
      unsigned h0, l0, h1, l1;
      bsplit(ve[d], h0, l0);
      bsplit(xa[d], h1, l1);
      xh_hi[obase + d * 128]      = (u16)h0;
      xh_lo[obase + d * 128]      = (u16)l0;
      xh_hi[obase + d * 128 + 64] = (u16)h1;
      xh_lo[obase + d * 128 + 64] = (u16)l1;
    }

    // gating: per-lane own-row reads (32B stride -> 2 lanes/line)
    float pl[8] = {0.f, 0.f, 0.f, 0.f, 0.f, 0.f, 0.f, 0.f};
#pragma unroll
    for (int d = 0; d < 8; ++d) {
      const float* w0 = Wg + (size_t)(d * 128 + l) * En;
      float4 wA = *(const float4*)w0;
      float4 wB = *(const float4*)(w0 + 4);
      float xv = ve[d];
      pl[0] += xv * wA.x; pl[1] += xv * wA.y; pl[2] += xv * wA.z; pl[3] += xv * wA.w;
      pl[4] += xv * wB.x; pl[5] += xv * wB.y; pl[6] += xv * wB.z; pl[7] += xv * wB.w;
      const float* w1 = Wg + (size_t)(d * 128 + 64 + l) * En;
      float4 wC = *(const float4*)w1;
      float4 wD = *(const float4*)(w1 + 4);
      xv = xa[d];
      pl[0] += xv * wC.x; pl[1] += xv * wC.y; pl[2] += xv * wC.z; pl[3] += xv * wC.w;
      pl[4] += xv * wD.x; pl[5] += xv * wD.y; pl[6] += xv * wD.z; pl[7] += xv * wD.w;
    }
#pragma unroll
    for (int off = 1; off < 64; off <<= 1) {
#pragma unroll
      for (int e = 0; e < 8; ++e) pl[e] += __shfl_xor(pl[e], off, 64);
    }
    float m = pl[0]; int be = 0;
#pragma unroll
    for (int e = 1; e < 8; ++e) if (pl[e] > m) { m = pl[e]; be = e; }   // first max wins
    float ss = 0.f;
#pragma unroll
    for (int e = 0; e < 8; ++e) ss += expf(pl[e] - m);
    if (l == 0) {
      expertArr[bs] = be;
      gateArr[bs] = 1.0f / ss;
    }
  } else if (bid < 2048 + 768) {
    int id = bid - 2048;               // 8 experts * (16 k-tiles * 6 c-tiles)
    int e = id / 96, r2 = id % 96;
    prep_body(Wqkv, WqT_hi, WqT_lo, Dn, 384, e, (r2 / 6) << 6, (r2 % 6) << 6, tile);
  } else {
    int id = bid - 2816;               // 8 experts * (2 k-tiles * 16 c-tiles)
    int e = id >> 5, r2 = id & 31;
    prep_body(Wff, WfT_hi, WfT_lo, HDn, Dn, e, (r2 >> 4) << 6, (r2 & 15) << 6, tile);
  }
}

// ---------------- K2: stable per-(b,e) token lists + tile table (last block) ----------------
__global__ __launch_bounds__(256) void k_route(
    const int* __restrict__ expertArr, int* __restrict__ idx, int* __restrict__ cnt,
    int* __restrict__ tileg, int* __restrict__ tilem, int* __restrict__ ntile,
    int* __restrict__ done)
{
  int g = blockIdx.x;
  int b = g >> 3, e = g & 7;
  int t = threadIdx.x;
  __shared__ int wtot[4];
  __shared__ int base;
  if (t == 0) base = 0;
  __syncthreads();
  for (int c = 0; c < Sn; c += 256) {
    int s = c + t;
    int pred = (expertArr[b * Sn + s] == e) ? 1 : 0;
    unsigned long long mask = __ballot(pred);
    int ln = t & 63, wv = t >> 6;
    int wpre = __popcll(mask & ((1ull << ln) - 1ull));
    if (ln == 63) wtot[wv] = wpre + pred;
    __syncthreads();
    int woff = 0;
    for (int w = 0; w < wv; ++w) woff += wtot[w];
    int tot = wtot[0] + wtot[1] + wtot[2] + wtot[3];
    if (pred) idx[(g << 11) + base + woff + wpre] = s;
    __syncthreads();
    if (t == 0) base += tot;
    __syncthreads();
  }
  if (t == 0) {
    cnt[g] = base;
    __threadfence();
    if (atomicAdd(done, 1) == NG - 1) {
      int tc = 0;
      for (int gg = 0; gg < NG; ++gg) {
        int nn = __hip_atomic_load(&cnt[gg], __ATOMIC_ACQUIRE, __HIP_MEMORY_SCOPE_AGENT);
        for (int m0 = 0; m0 < nn && tc < MAXT; m0 += 64) { tileg[tc] = gg; tilem[tc] = m0; ++tc; }
      }
      ntile[0] = tc;
    }
  }
}

// ------- K3: grouped QKV GEMM, MFMA bf16x3, BM=64 x BN=192 x BK=32 -------
// Counted-vmcnt pipeline (T4): 8 global_load_lds per wave per iter; never drain
// to 0 in the main loop. Raw s_barrier + lgkmcnt-only drain for read-protect.
__global__ __launch_bounds__(256) void k_qkv(
    const u16* __restrict__ xh_hi, const u16* __restrict__ xh_lo,
    const u16* __restrict__ WqT_hi, const u16* __restrict__ WqT_lo,
    const int* __restrict__ idx, const int* __restrict__ cnt,
    u16* __restrict__ qkv_hi, u16* __restrict__ qkv_lo,
    u16* __restrict__ vT_hi, u16* __restrict__ vT_lo)
{
  extern __shared__ unsigned char LDS[];
  int bid = blockIdx.x;            // 384 = 8 xcd * 4 groups * 12 slots
  int r8 = bid & 7, q = bid >> 3;  // q 0..47
  int g = r8 + ((q & 3) << 3);     // all 32 groups
  int slot = q >> 2;               // 0..11
  int m0 = (slot >> 1) << 6;       // 6 m-tiles (covers n<=384)
  int n0 = (slot & 1) * 192;       // 2 n0 passes
  int n = cnt[g];
  if (m0 >= n) return;
  int b = g >> 3, e = g & 7;
  const int* idxg = idx + (g << 11);
  int t = threadIdx.x;
  int w = t >> 6, l = t & 63;
  int lc = l & 15, lq = l >> 4;

  int srow = t >> 2;
  int sslot = (t & 3) ^ ((srow >> 1) & 3);
  int rgs = m0 + srow; rgs = rgs < n ? rgs : n - 1;
  size_t aoffR = ((size_t)(b * Sn + idxg[rgs])) * Dn + sslot * 8;
  size_t boffR0 = ((size_t)e * 384 + n0 + srow) * Dn + sslot * 8;
  unsigned dst = (unsigned)t << 4;

  f32x4 acc[4][3];
#pragma unroll
  for (int i = 0; i < 4; ++i)
#pragma unroll
    for (int j = 0; j < 3; ++j) acc[i][j] = (f32x4){0.f, 0.f, 0.f, 0.f};

  unsigned off = (unsigned)((lq ^ ((lc >> 1) & 3)) << 4);

#define STAGE(bb, k0)                                                 \
  do {                                                                \
    gl16(xh_hi + aoffR + (k0), LDS + (bb) + dst);                     \
    gl16(xh_lo + aoffR + (k0), LDS + (bb) + 4096 + dst);              \
    gl16(WqT_hi + boffR0 + (k0), LDS + (bb) + 8192 + dst);            \
    gl16(WqT_hi + boffR0 + (size_t)64 * Dn + (k0), LDS + (bb) + 12288 + dst); \
    gl16(WqT_hi + boffR0 + (size_t)128 * Dn + (k0), LDS + (bb) + 16384 + dst);\
    gl16(WqT_lo + boffR0 + (k0), LDS + (bb) + 20480 + dst);           \
    gl16(WqT_lo + boffR0 + (size_t)64 * Dn + (k0), LDS + (bb) + 24576 + dst); \
    gl16(WqT_lo + boffR0 + (size_t)128 * Dn + (k0), LDS + (bb) + 28672 + dst);\
  } while (0)

  STAGE(0, 0);
  asm volatile("s_waitcnt vmcnt(0)" ::: "memory");
  __builtin_amdgcn_s_barrier();
  for (int tt = 0; tt < 32; ++tt) {
    unsigned cur = (tt & 1) ? 32768u : 0u;
    if (tt < 31) {
      STAGE(cur ^ 32768u, (tt + 1) * 32);
      asm volatile("s_waitcnt vmcnt(8)" ::: "memory");   // current tile's 8 done
    } else {
      asm volatile("s_waitcnt vmcnt(0)" ::: "memory");
    }
    __builtin_amdgcn_s_barrier();                        // cur buffer ready
    bf16x8 ah[4], al[4], bh[3], bl[3];
#pragma unroll
    for (int fi = 0; fi < 4; ++fi) {
      unsigned ab = cur + (unsigned)((fi * 16 + lc) * 64) + off;
      ah[fi] = *(const bf16x8*)(LDS + ab);
      al[fi] = *(const bf16x8*)(LDS + ab + 4096);
    }
#pragma unroll
    for (int fj = 0; fj < 3; ++fj) {
      unsigned bb2 = cur + 8192u + (unsigned)((w * 48 + fj * 16 + lc) * 64) + off;
      bh[fj] = *(const bf16x8*)(LDS + bb2);
      bl[fj] = *(const bf16x8*)(LDS + bb2 + 12288);
    }
    __builtin_amdgcn_s_setprio(1);
#pragma unroll
    for (int fi = 0; fi < 4; ++fi)
#pragma unroll
      for (int fj = 0; fj < 3; ++fj) {
        acc[fi][fj] = MFMA16(ah[fi], bh[fj], acc[fi][fj]);
        acc[fi][fj] = MFMA16(al[fi], bh[fj], acc[fi][fj]);
        acc[fi][fj] = MFMA16(ah[fi], bl[fj], acc[fi][fj]);
      }
    __builtin_amdgcn_s_setprio(0);
    asm volatile("s_waitcnt lgkmcnt(0)" ::: "memory");   // ds_reads drained
    __builtin_amdgcn_sched_barrier(0);
    __builtin_amdgcn_s_barrier();                        // safe to overwrite cur
  }
#undef STAGE

#pragma unroll
  for (int fi = 0; fi < 4; ++fi) {
#pragma unroll
    for (int rr = 0; rr < 4; ++rr) {
      int rg = m0 + fi * 16 + lq * 4 + rr;
      if (rg < n) {
        int tok = idxg[rg];
#pragma unroll
        for (int fj = 0; fj < 3; ++fj) {
          int col = n0 + w * 48 + fj * 16 + lc;
          unsigned h, lo2;
          bsplit(acc[fi][fj][rr], h, lo2);
          if (col < 256) {
            size_t o = (size_t)(b * Sn + tok) * 384 + col;
            qkv_hi[o] = (u16)h; qkv_lo[o] = (u16)lo2;
          } else {
            size_t o = ((size_t)g * HDn + (col - 256)) * MAXN + rg;
            vT_hi[o] = (u16)h; vT_lo[o] = (u16)lo2;
          }
        }
      }
    }
  }
}

// ------- K4: grouped flash attention via MFMA bf16x3 (+T5 setprio) -------
__global__ __launch_bounds__(256) void k_attn(
    const u16* __restrict__ qkv_hi, const u16* __restrict__ qkv_lo,
    const u16* __restrict__ vT_hi, const u16* __restrict__ vT_lo,
    const int* __restrict__ idx, const int* __restrict__ cnt,
    const int* __restrict__ tileg, const int* __restrict__ tilem,
    const int* __restrict__ ntile,
    u16* __restrict__ ctx_hi, u16* __restrict__ ctx_lo)
{
  extern __shared__ unsigned char LDS[];
  int tid = blockIdx.x;
  if (tid >= ntile[0]) return;
  int g = tileg[tid], m0 = tilem[tid];
  int n = cnt[g];
  int b = g >> 3;
  const int* idxg = idx + (g << 11);
  int t = threadIdx.x, wid = t >> 6, l = t & 63;
  int lc = l & 15, lq = l >> 4;
  const float scale = 0.08838834764831845f;   // 1/sqrt(128)

  int qrg = m0 + wid * 16 + lc; qrg = qrg < n ? qrg : n - 1;
  size_t qoff = (size_t)(b * Sn + idxg[qrg]) * 384 + lq * 8;
  bf16x8 Qhi[4], Qlo[4];
#pragma unroll
  for (int ks = 0; ks < 4; ++ks) {
    Qhi[ks] = *(const bf16x8*)(qkv_hi + qoff + ks * 32);
    Qlo[ks] = *(const bf16x8*)(qkv_lo + qoff + ks * 32);
  }

  f32x4 acc[8];
#pragma unroll
  for (int i = 0; i < 8; ++i) acc[i] = (f32x4){0.f, 0.f, 0.f, 0.f};
  float m_r[4] = {-1e30f, -1e30f, -1e30f, -1e30f};
  float l_r[4] = {0.f, 0.f, 0.f, 0.f};

  size_t vbase = ((size_t)g * HDn + lc) * MAXN + lq * 8;
  unsigned pbase = 65536u + wid * 4096u;

#define STAGEK(bufb, kc)                                                     \
  do {                                                                       \
    unsigned bb = (bufb);                                                    \
    for (int j = 0; j < 4; ++j) {                                            \
      int c = wid * 4 + j;                                                   \
      int row = (kc) + c * 4 + lq;                                           \
      int rg = row < n ? row : n - 1;                                        \
      int srcslot = lc ^ (((c & 1) << 2) | lq);                              \
      size_t soff = (size_t)(b * Sn + idxg[rg]) * 384 + 128 + srcslot * 8;   \
      gl16(qkv_hi + soff, LDS + bb + c * 1024);                              \
      gl16(qkv_lo + soff, LDS + bb + 16384 + c * 1024);                      \
    }                                                                        \
  } while (0)

  int nt = (n + 63) >> 6;
  STAGEK(0, 0);
  __syncthreads();

  for (int tt = 0; tt < nt; ++tt) {
    unsigned cur = (tt & 1) ? 32768u : 0u;
    if (tt + 1 < nt) STAGEK(cur ^ 32768u, (tt + 1) * 64);
    int kc = tt * 64;

    f32x4 Sf[4];
#pragma unroll
    for (int kf = 0; kf < 4; ++kf) Sf[kf] = (f32x4){0.f, 0.f, 0.f, 0.f};
    __builtin_amdgcn_s_setprio(1);
#pragma unroll
    for (int ks = 0; ks < 4; ++ks) {
#pragma unroll
      for (int kf = 0; kf < 4; ++kf) {
        int row = kf * 16 + lc;
        unsigned byte = cur + row * 256 + ((((ks << 2) | lq) ^ (row & 7)) << 4);
        bf16x8 kh = *(const bf16x8*)(LDS + byte);
        bf16x8 kl = *(const bf16x8*)(LDS + byte + 16384);
        Sf[kf] = MFMA16(Qhi[ks], kh, Sf[kf]);
        Sf[kf] = MFMA16(Qlo[ks], kh, Sf[kf]);
        Sf[kf] = MFMA16(Qhi[ks], kl, Sf[kf]);
      }
    }
    __builtin_amdgcn_s_setprio(0);

    float mloc[4] = {-1e30f, -1e30f, -1e30f, -1e30f};
#pragma unroll
    for (int kf = 0; kf < 4; ++kf) {
#pragma unroll
      for (int r = 0; r < 4; ++r) {
        int key = kc + kf * 16 + lc;
        float s = (key < n) ? Sf[kf][r] * scale : -1e30f;
        Sf[kf][r] = s;
        mloc[r] = fmaxf(mloc[r], s);
      }
    }
#pragma unroll
    for (int off = 1; off < 16; off <<= 1) {
#pragma unroll
      for (int r = 0; r < 4; ++r) mloc[r] = fmaxf(mloc[r], __shfl_xor(mloc[r], off, 64));
    }
    float corr[4], rs[4] = {0.f, 0.f, 0.f, 0.f};
#pragma unroll
    for (int r = 0; r < 4; ++r) {
      float mn = fmaxf(m_r[r], mloc[r]);
      corr[r] = expf(m_r[r] - mn);
      m_r[r] = mn;
    }
#pragma unroll
    for (int kf = 0; kf < 4; ++kf) {
#pragma unroll
      for (int r = 0; r < 4; ++r) {
        float p = expf(Sf[kf][r] - m_r[r]);
        rs[r] += p;
        unsigned ph, plo;
        bsplit(p, ph, plo);
        int prow = (lq << 2) | r;
        int slot = (kf << 1) | (lc >> 3);
        unsigned pb = pbase + prow * 128 + ((slot ^ (prow & 7)) << 4) + ((lc & 7) << 1);
        *(u16*)(LDS + pb) = (u16)ph;
        *(u16*)(LDS + pb + 2048) = (u16)plo;
      }
    }
#pragma unroll
    for (int off = 1; off < 16; off <<= 1) {
#pragma unroll
      for (int r = 0; r < 4; ++r) rs[r] += __shfl_xor(rs[r], off, 64);
    }
#pragma unroll
    for (int r = 0; r < 4; ++r) l_r[r] = l_r[r] * corr[r] + rs[r];
#pragma unroll
    for (int df = 0; df < 8; ++df)
#pragma unroll
      for (int r = 0; r < 4; ++r) acc[df][r] *= corr[r];

#pragma unroll
    for (int ks2 = 0; ks2 < 2; ++ks2) {
      unsigned pr = pbase + lc * 128 + ((((ks2 << 2) | lq) ^ (lc & 7)) << 4);
      bf16x8 pa = *(const bf16x8*)(LDS + pr);
      bf16x8 pl = *(const bf16x8*)(LDS + pr + 2048);
      __builtin_amdgcn_s_setprio(1);
#pragma unroll
      for (int df = 0; df < 8; ++df) {
        size_t vo = vbase + (size_t)(df * 16) * MAXN + kc + ks2 * 32;
        bf16x8 vh = *(const bf16x8*)(vT_hi + vo);
        bf16x8 vl = *(const bf16x8*)(vT_lo + vo);
        acc[df] = MFMA16(pa, vh, acc[df]);
        acc[df] = MFMA16(pl, vh, acc[df]);
        acc[df] = MFMA16(pa, vl, acc[df]);
      }
      __builtin_amdgcn_s_setprio(0);
    }
    __syncthreads();
  }
#undef STAGEK

#pragma unroll
  for (int r = 0; r < 4; ++r) {
    int rg = m0 + wid * 16 + (lq << 2) + r;
    if (rg < n) {
      int tok = idxg[rg];
      float inv = 1.0f / l_r[r];
      size_t o = (size_t)(b * Sn + tok) * HDn + lc;
#pragma unroll
      for (int df = 0; df < 8; ++df) {
        unsigned h, lo2;
        bsplit(acc[df][r] * inv, h, lo2);
        ctx_hi[o + df * 16] = (u16)h;
        ctx_lo[o + df * 16] = (u16)lo2;
      }
    }
  }
}

// ---------------- K5: out projection via MFMA bf16x3 + gate + scatter ----------------
__global__ __launch_bounds__(256) void k_out(
    const u16* __restrict__ ctx_hi, const u16* __restrict__ ctx_lo,
    const u16* __restrict__ WfT_hi, const u16* __restrict__ WfT_lo,
    const float* __restrict__ bff,
    const int* __restrict__ idx, const int* __restrict__ cnt,
    const int* __restrict__ tileg, const int* __restrict__ tilem,
    const int* __restrict__ ntile,
    const float* __restrict__ gateArr,
    float* __restrict__ out)
{
  int tid = blockIdx.x;
  if (tid >= ntile[0]) return;
  int g = tileg[tid], m0 = tilem[tid];
  int n = cnt[g];
  int b = g >> 3, e = g & 7;
  const int* idxg = idx + (g << 11);
  int t = threadIdx.x, wid = t >> 6, l = t & 63;
  int lc = l & 15, lq = l >> 4;
  int n0 = blockIdx.y * 256 + wid * 64;

  f32x4 acc[4][4];
#pragma unroll
  for (int i = 0; i < 4; ++i)
#pragma unroll
    for (int j = 0; j < 4; ++j) acc[i][j] = (f32x4){0.f, 0.f, 0.f, 0.f};

  size_t aoff[4];
#pragma unroll
  for (int fi = 0; fi < 4; ++fi) {
    int rg = m0 + fi * 16 + lc; rg = rg < n ? rg : n - 1;
    aoff[fi] = ((size_t)(b * Sn + idxg[rg])) * HDn + lq * 8;
  }
  size_t boff[4];
#pragma unroll
  for (int fj = 0; fj < 4; ++fj)
    boff[fj] = ((size_t)e * Dn + n0 + fj * 16 + lc) * HDn + lq * 8;

#pragma unroll
  for (int ks = 0; ks < 4; ++ks) {
    int ko = ks * 32;
    bf16x8 ah[4], al[4], bh[4], bl[4];
#pragma unroll
    for (int fi = 0; fi < 4; ++fi) {
      ah[fi] = *(const bf16x8*)(ctx_hi + aoff[fi] + ko);
      al[fi] = *(const bf16x8*)(ctx_lo + aoff[fi] + ko);
    }
#pragma unroll
    for (int fj = 0; fj < 4; ++fj) {
      bh[fj] = *(const bf16x8*)(WfT_hi + boff[fj] + ko);
      bl[fj] = *(const bf16x8*)(WfT_lo + boff[fj] + ko);
    }
#pragma unroll
    for (int fi = 0; fi < 4; ++fi)
#pragma unroll
      for (int fj = 0; fj < 4; ++fj) {
        acc[fi][fj] = MFMA16(ah[fi], bh[fj], acc[fi][fj]);
        acc[fi][fj] = MFMA16(al[fi], bh[fj], acc[fi][fj]);
        acc[fi][fj] = MFMA16(ah[fi], bl[fj], acc[fi][fj]);
      }
  }

  float bv[4];
#pragma unroll
  for (int fj = 0; fj < 4; ++fj) bv[fj] = bff[n0 + fj * 16 + lc];

#pragma unroll
  for (int fi = 0; fi < 4; ++fi) {
#pragma unroll
    for (int rr = 0; rr < 4; ++rr) {
      int rg = m0 + fi * 16 + lq * 4 + rr;
      if (rg < n) {
        int tok = idxg[rg];
        float gt = gateArr[b * Sn + tok];
        float* orow = out + ((size_t)(b * Sn + tok)) * Dn + n0 + lc;
#pragma unroll
        for (int fj = 0; fj < 4; ++fj)
          orow[fj * 16] = (acc[fi][fj][rr] + bv[fj]) * gt;
      }
    }
  }
}

extern "C" void kernel_launch(void* const* d_in, const int* in_sizes, int n_in,
                              void* d_out, int out_size, void* d_ws, size_t ws_size,
                              hipStream_t stream) {
  const float* x    = (const float*)d_in[0];
  const float* Wg   = (const float*)d_in[1];
  const float* Wqkv = (const float*)d_in[2];
  const float* Wff  = (const float*)d_in[3];
  const float* bff  = (const float*)d_in[4];
  const float* cosT = (const float*)d_in[5];
  const float* sinT = (const float*)d_in[6];
  float* out = (float*)d_out;

  size_t off = 0;
  auto carve = [&](size_t bytes) -> void* {
    void* p = (char*)d_ws + off;
    off += (bytes + 255) & ~(size_t)255;
    return p;
  };
  u16* xh_hi  = (u16*)carve((size_t)Bn * Sn * Dn * 2);
  u16* xh_lo  = (u16*)carve((size_t)Bn * Sn * Dn * 2);
  u16* WqT_hi = (u16*)carve((size_t)En * 384 * Dn * 2);
  u16* WqT_lo = (u16*)carve((size_t)En * 384 * Dn * 2);
  u16* WfT_hi = (u16*)carve((size_t)En * Dn * HDn * 2);
  u16* WfT_lo = (u16*)carve((size_t)En * Dn * HDn * 2);
  u16* qkv_hi = (u16*)carve((size_t)Bn * Sn * 384 * 2);
  u16* qkv_lo = (u16*)carve((size_t)Bn * Sn * 384 * 2);
  u16* vT_hi  = (u16*)carve((size_t)NG * HDn * MAXN * 2);
  u16* vT_lo  = (u16*)carve((size_t)NG * HDn * MAXN * 2);
  u16* ctx_hi = (u16*)carve((size_t)Bn * Sn * HDn * 2);
  u16* ctx_lo = (u16*)carve((size_t)Bn * Sn * HDn * 2);
  float* gateArr = (float*)carve((size_t)Bn * Sn * sizeof(float));
  int*   expertA = (int*)carve((size_t)Bn * Sn * sizeof(int));
  int*   idx     = (int*)carve((size_t)NG * Sn * sizeof(int));
  int*   cnt     = (int*)carve((size_t)NG * sizeof(int));
  int*   tileg   = (int*)carve((size_t)MAXT * sizeof(int));
  int*   tilem   = (int*)carve((size_t)MAXT * sizeof(int));
  int*   ntile   = (int*)carve(256);
  int*   done    = (int*)carve(256);
  (void)ws_size; (void)in_sizes; (void)n_in; (void)out_size;

  hipFuncSetAttribute((const void*)k_attn, hipFuncAttributeMaxDynamicSharedMemorySize, 81920);

  k_prologue<<<dim3(3072), dim3(256), 0, stream>>>(x, Wg, cosT, sinT, Wqkv, Wff,
      xh_hi, xh_lo, WqT_hi, WqT_lo, WfT_hi, WfT_lo, expertA, gateArr, done);
  k_route<<<dim3(NG), dim3(256), 0, stream>>>(expertA, idx, cnt, tileg, tilem, ntile, done);
  k_qkv<<<dim3(384), dim3(256), 65536, stream>>>(xh_hi, xh_lo, WqT_hi, WqT_lo, idx, cnt, qkv_hi, qkv_lo, vT_hi, vT_lo);
  k_attn<<<dim3(MAXT), dim3(256), 81920, stream>>>(qkv_hi, qkv_lo, vT_hi, vT_lo, idx, cnt, tileg, tilem, ntile, ctx_hi, ctx_lo);
  k_out<<<dim3(MAXT, 4), dim3(256), 0, stream>>>(ctx_hi, ctx_lo, WfT_hi, WfT_lo, bff, idx, cnt, tileg, tilem, ntile, gateArr, out);
}